// Round 17
// baseline (540.810 us; speedup 1.0000x reference)
//
#include <hip/hip_runtime.h>
#include <hip/hip_bf16.h>
#include <cstdint>

// GraphTransformerLinkPredictor on MI355X.
// bf16-canonical h. fused MFMA input proj (512-thread blocks, lazy ds_read,
// direct stores) -> bucketed CSR build + degree-sorted perm -> 2x { gemm4
// MFMA bf16 (16KB LDS, lazy fragments, direct stores: q int8, k int8 + v fp8
// kvb, hsb = h + skip) -> fused edge attn+LN (16-lane quarter owns one node;
// sdot4 score; packed-fp16 v accumulate; 1-deep kv pipeline) } -> pair dot.
// Softmax identity: alpha = exp(s)/sum(exp(s)) (scores bounded, no max pass).

#define NN      100000
#define EE      1000000
#define RWSEC   16
#define WALKC   16
#define NPAIRSC 200000
#define BSH     9                       // 512 nodes per bucket
#define BKT     ((NN + 511) >> BSH)     // 196

typedef unsigned int       u32;
typedef unsigned short     u16;
typedef unsigned char      u8;
typedef __attribute__((ext_vector_type(8))) short    short8;
typedef __attribute__((ext_vector_type(4))) float    f32x4;
typedef __attribute__((ext_vector_type(2))) _Float16 h2;

__device__ __forceinline__ float bflo(u32 u){ return __uint_as_float(u << 16); }
__device__ __forceinline__ float bfhi(u32 u){ return __uint_as_float(u & 0xffff0000u); }
__device__ __forceinline__ u16 f2bf(float f){
    u32 u = __float_as_uint(f);
    u += 0x7fffu + ((u >> 16) & 1u);   // round-to-nearest-even
    return (u16)(u >> 16);
}
__device__ __forceinline__ u32 pack2(float a, float b){
    return (u32)f2bf(a) | ((u32)f2bf(b) << 16);
}

// ---- fp8 e4m3 + int8 helpers (HW cvt on gfx950; manual fallback) ----
#if defined(__has_builtin)
#if __has_builtin(__builtin_amdgcn_cvt_pk_f32_fp8) && __has_builtin(__builtin_amdgcn_cvt_pk_fp8_f32)
#define HWFP8 1
#endif
#if __has_builtin(__builtin_amdgcn_sdot4)
#define USE_SDOT4 1
#endif
#if __has_builtin(__builtin_amdgcn_cvt_pk_f16_fp8)
#define HWF16FP8 1
#endif
#endif

#ifndef HWFP8
__device__ __forceinline__ float fp8dec1(u32 b){
    u32 s = (b >> 7) & 1u, e = (b >> 3) & 15u, m = b & 7u;
    float mag = e ? __uint_as_float(((e + 120u) << 23) | (m << 20))
                  : (float)m * 0.001953125f;
    return s ? -mag : mag;
}
__device__ __forceinline__ u32 fp8enc1(float f){
    u32 u = __float_as_uint(f); u32 s = (u >> 31) << 7; float a = fabsf(f);
    if (a >= 448.f) return s | 0x7Eu;
    u32 ua = __float_as_uint(a);
    ua += 0x7FFFFu + ((ua >> 20) & 1u);
    int e = (int)(ua >> 23) - 127 + 7;
    if (e <= 0){ int m = (int)rintf(a * 512.f); return s | (u32)m; }
    u32 m = (ua >> 20) & 7u;
    return s | ((u32)e << 3) | m;
}
#endif

__device__ __forceinline__ void fp8x4_dec(u32 w4, float& f0, float& f1, float& f2, float& f3){
#ifdef HWFP8
    auto lo = __builtin_amdgcn_cvt_pk_f32_fp8((int)w4, false);
    auto hi = __builtin_amdgcn_cvt_pk_f32_fp8((int)w4, true);
    f0 = lo[0]; f1 = lo[1]; f2 = hi[0]; f3 = hi[1];
#else
    f0 = fp8dec1(w4 & 255u); f1 = fp8dec1((w4 >> 8) & 255u);
    f2 = fp8dec1((w4 >> 16) & 255u); f3 = fp8dec1(w4 >> 24);
#endif
}
__device__ __forceinline__ u32 fp8x4_enc(float f0, float f1, float f2, float f3){
#ifdef HWFP8
    u32 t = (u32)__builtin_amdgcn_cvt_pk_fp8_f32(f0, f1, 0, false);
    return (u32)__builtin_amdgcn_cvt_pk_fp8_f32(f2, f3, (int)t, true);
#else
    return fp8enc1(f0) | (fp8enc1(f1) << 8) | (fp8enc1(f2) << 16) | (fp8enc1(f3) << 24);
#endif
}
// decode 4 fp8 -> 2 packed half2 (bit_cast: pkrtz returns __fp16x2, same layout)
__device__ __forceinline__ void fp8x4_to_h2(u32 w, h2& lo, h2& hi){
#ifdef HWF16FP8
    lo = __builtin_bit_cast(h2, __builtin_amdgcn_cvt_pk_f16_fp8((int)w, false));
    hi = __builtin_bit_cast(h2, __builtin_amdgcn_cvt_pk_f16_fp8((int)w, true));
#else
    float f0, f1, f2, f3;
    fp8x4_dec(w, f0, f1, f2, f3);
    lo = __builtin_bit_cast(h2, __builtin_amdgcn_cvt_pkrtz(f0, f1));
    hi = __builtin_bit_cast(h2, __builtin_amdgcn_cvt_pkrtz(f2, f3));
#endif
}

#define QSCALE    48.0f
#define DESCALE2  1.10693e-4f           // log2(e)/(48*48*sqrt(32))

__device__ __forceinline__ int i8q(float f){
    float c = fminf(fmaxf(f * QSCALE, -127.f), 127.f);
    return (int)rintf(c);
}
__device__ __forceinline__ u32 i8x4_enc(float f0, float f1, float f2, float f3){
    return (u32)(i8q(f0) & 255) | ((u32)(i8q(f1) & 255) << 8)
         | ((u32)(i8q(f2) & 255) << 16) | ((u32)(i8q(f3) & 255) << 24);
}
__device__ __forceinline__ float sb(u32 w, int i){
    return (float)(int)(signed char)((w >> (i * 8)) & 255u);
}

// ---------------- W_in prep: per-lane MFMA fragments, K padded 144->160 ----------------
__global__ __launch_bounds__(256) void winprep_kernel(const float* __restrict__ Win,
                                                      u16* __restrict__ Winb){
    int t = blockIdx.x * 256 + threadIdx.x;
    if (t >= 8 * 5 * 64) return;
    int lane = t & 63, fi = t >> 6;          // fi = nt*5+kk
    int nt = fi / 5, kk = fi - nt * 5;
    int col = nt * 16 + (lane & 15);
    int k0  = kk * 32 + (lane >> 4) * 8;
    u16* dst = Winb + (size_t)fi * 512 + lane * 8;
    #pragma unroll
    for (int e = 0; e < 8; ++e){
        int k = k0 + e;
        dst[e] = (k < 144) ? f2bf(Win[(size_t)k * 128 + col]) : (u16)0;
    }
}

// ---------------- fused input proj (MFMA): hb = bf16(concat(x, rw@Wr+br) @ W_in + b_in) ----------------
__global__ __launch_bounds__(512, 8) void inproj_mfma(const float* __restrict__ x,
        const float* __restrict__ rw, const float* __restrict__ Wr,
        const float* __restrict__ br,
        const u16* __restrict__ Winb, const float* __restrict__ bin,
        u16* __restrict__ hb){
    __shared__ u16   hs[64 * 168];     // row stride 336 B, cols 0..159
    __shared__ float rws[64 * 16];
    int tid = threadIdx.x;
    int n0  = blockIdx.x * 64;

    #pragma unroll
    for (int i = 0; i < 4; ++i){
        int g   = i * 512 + tid;
        int row = g >> 5, c4 = g & 31;
        float4 f = make_float4(0.f, 0.f, 0.f, 0.f);
        if (n0 + row < NN)
            f = *reinterpret_cast<const float4*>(x + (size_t)(n0 + row) * 128 + c4 * 4);
        *reinterpret_cast<uint2*>((char*)hs + row * 336 + c4 * 8)
            = make_uint2(pack2(f.x, f.y), pack2(f.z, f.w));
    }
    if (tid < 256){
        int row = tid >> 2, c4 = tid & 3;
        float4 f = make_float4(0.f, 0.f, 0.f, 0.f);
        if (n0 + row < NN)
            f = *reinterpret_cast<const float4*>(rw + (size_t)(n0 + row) * 16 + c4 * 4);
        *reinterpret_cast<float4*>(&rws[row * 16 + c4 * 4]) = f;
    }
    __syncthreads();
    if (tid < 256){
        int row = tid >> 2, j0 = (tid & 3) * 4;
        float p0 = br[j0], p1 = br[j0 + 1], p2 = br[j0 + 2], p3 = br[j0 + 3];
        #pragma unroll
        for (int w = 0; w < 16; ++w){
            float r = rws[row * 16 + w];
            const float4 wv = *reinterpret_cast<const float4*>(Wr + w * 16 + j0);
            p0 = fmaf(r, wv.x, p0); p1 = fmaf(r, wv.y, p1);
            p2 = fmaf(r, wv.z, p2); p3 = fmaf(r, wv.w, p3);
        }
        *reinterpret_cast<uint2*>((char*)hs + row * 336 + 256 + (tid & 3) * 8)
            = make_uint2(pack2(p0, p1), pack2(p2, p3));
        *reinterpret_cast<uint2*>((char*)hs + row * 336 + 288 + (tid & 3) * 8)
            = make_uint2(0u, 0u);
    }
    __syncthreads();

    int l = tid & 63, w = tid >> 6;    // wave w owns nt = w
    int r16 = l & 15, kq = l >> 4;
    const short8* wfrag = reinterpret_cast<const short8*>(Winb) + (size_t)(w * 5) * 64;
    f32x4 acc[4];
    #pragma unroll
    for (int rg = 0; rg < 4; ++rg) acc[rg] = (f32x4){0.f, 0.f, 0.f, 0.f};
    for (int kk = 0; kk < 5; ++kk){
        short8 wf = wfrag[kk * 64 + l];
        #pragma unroll
        for (int rg = 0; rg < 4; ++rg){
            int row = rg * 16 + r16;
            short8 hf = *reinterpret_cast<const short8*>(
                (const char*)hs + row * 336 + kk * 64 + kq * 16);
            acc[rg] = __builtin_amdgcn_mfma_f32_16x16x32_bf16(wf, hf, acc[rg], 0, 0, 0);
        }
    }
    float4 bv = *reinterpret_cast<const float4*>(bin + w * 16 + kq * 4);
    #pragma unroll
    for (int rg = 0; rg < 4; ++rg){
        int row = rg * 16 + r16;
        if (n0 + row < NN){
            u32 lo = pack2(acc[rg][0] + bv.x, acc[rg][1] + bv.y);
            u32 hi = pack2(acc[rg][2] + bv.z, acc[rg][3] + bv.w);
            *reinterpret_cast<uint2*>(hb + (size_t)(n0 + row) * 128 + w * 16 + kq * 4)
                = make_uint2(lo, hi);
        }
    }
}

// ---------------- bucketed CSR build (u32-packed records) ----------------
__global__ __launch_bounds__(256) void bhist_kernel(const int* __restrict__ col,
                                                    int* __restrict__ bcnt){
    __shared__ int h[BKT];
    int tid = threadIdx.x;
    for (int i = tid; i < BKT; i += 256) h[i] = 0;
    __syncthreads();
    for (int e = blockIdx.x * 256 + tid; e < EE; e += gridDim.x * 256)
        atomicAdd(&h[col[e] >> BSH], 1);
    __syncthreads();
    for (int i = tid; i < BKT; i += 256)
        if (h[i]) atomicAdd(&bcnt[i], h[i]);
}

__global__ __launch_bounds__(256) void bscan_kernel(const int* __restrict__ bcnt,
                                                    int* __restrict__ bstart,
                                                    int* __restrict__ bwork){
    __shared__ int lds[256];
    int tid = threadIdx.x;
    int v = (tid < BKT) ? bcnt[tid] : 0;
    lds[tid] = v;
    __syncthreads();
    for (int off = 1; off < 256; off <<= 1){
        int y = (tid >= off) ? lds[tid - off] : 0;
        __syncthreads();
        lds[tid] += y;
        __syncthreads();
    }
    if (tid < BKT){ int p = lds[tid] - v; bstart[tid] = p; bwork[tid] = p; }
}

__global__ __launch_bounds__(256) void bpart_kernel(const int* __restrict__ ei,
                                                    int* __restrict__ bwork,
                                                    u32* __restrict__ bkt){
    __shared__ int cnt_[BKT], base_[BKT], rnk_[BKT];
    int tid = threadIdx.x;
    for (int i = tid; i < BKT; i += 256){ cnt_[i] = 0; rnk_[i] = 0; }
    __syncthreads();
    for (int e = blockIdx.x * 256 + tid; e < EE; e += gridDim.x * 256)
        atomicAdd(&cnt_[ei[EE + e] >> BSH], 1);
    __syncthreads();
    for (int i = tid; i < BKT; i += 256)
        base_[i] = cnt_[i] ? atomicAdd(&bwork[i], cnt_[i]) : 0;
    __syncthreads();
    for (int e = blockIdx.x * 256 + tid; e < EE; e += gridDim.x * 256){
        int c = ei[EE + e], b = c >> BSH;
        int p = base_[b] + atomicAdd(&rnk_[b], 1);
        bkt[p] = ((u32)ei[e] << BSH) | (u32)(c & 511);   // row(17b) | col-in-bucket(9b)
    }
}

// one block per bucket: build deg/offs/ebuf with LDS atomics + LDS scan
// ebuf stores BYTE offsets (r*256) for direct kvb addressing in attn.
__global__ __launch_bounds__(256) void bcsr_kernel(const int* __restrict__ bstart,
                                                   const int* __restrict__ bcnt,
                                                   const u32* __restrict__ bkt,
                                                   int* __restrict__ offs,
                                                   int* __restrict__ deg,
                                                   int* __restrict__ ebuf){
    __shared__ int dcnt[512];
    __shared__ int pref[512];
    __shared__ int psum[256];
    int b   = blockIdx.x;
    int tid = threadIdx.x;
    int n0  = b << BSH;
    int nb  = NN - n0 < 512 ? NN - n0 : 512;
    int e0  = bstart[b];
    int ec  = bcnt[b];
    dcnt[tid] = 0; dcnt[tid + 256] = 0;
    __syncthreads();
    for (int i = tid; i < ec; i += 256)
        atomicAdd(&dcnt[bkt[e0 + i] & 511u], 1);
    __syncthreads();
    int s0 = dcnt[2 * tid], s1 = dcnt[2 * tid + 1];
    psum[tid] = s0 + s1;
    __syncthreads();
    for (int off = 1; off < 256; off <<= 1){
        int y = (tid >= off) ? psum[tid - off] : 0;
        __syncthreads();
        psum[tid] += y;
        __syncthreads();
    }
    int exq = psum[tid] - (s0 + s1);
    pref[2 * tid]     = exq;
    pref[2 * tid + 1] = exq + s0;
    __syncthreads();
    for (int i = tid; i < nb; i += 256){
        offs[n0 + i] = e0 + pref[i];
        deg[n0 + i]  = dcnt[i];
    }
    __syncthreads();
    for (int i = tid; i < ec; i += 256){
        u32 rc = bkt[e0 + i];
        int p = atomicAdd(&pref[rc & 511u], 1);
        ebuf[e0 + p] = (int)((rc >> BSH) << 8);   // r * 256 byte offset
    }
}

// ---------------- degree-sorted node permutation (counting sort, 256 bins) ----------------
__global__ __launch_bounds__(256) void dhist_kernel(const int* __restrict__ deg,
                                                    int* __restrict__ dh){
    __shared__ int h[256];
    int tid = threadIdx.x;
    h[tid] = 0;
    __syncthreads();
    for (int i = blockIdx.x * 256 + tid; i < NN; i += gridDim.x * 256){
        int d = deg[i]; d = d > 255 ? 255 : d;
        atomicAdd(&h[d], 1);
    }
    __syncthreads();
    if (h[tid]) atomicAdd(&dh[tid], h[tid]);
}

__global__ __launch_bounds__(256) void dscan_kernel(const int* __restrict__ dh,
                                                    int* __restrict__ dcur){
    __shared__ int lds[256];
    int tid = threadIdx.x;
    int v = dh[tid];
    lds[tid] = v;
    __syncthreads();
    for (int off = 1; off < 256; off <<= 1){
        int y = (tid >= off) ? lds[tid - off] : 0;
        __syncthreads();
        lds[tid] += y;
        __syncthreads();
    }
    dcur[tid] = lds[tid] - v;
}

// block-reserved scatter (bpart pattern): LDS count -> one global reservation
// per populated bin per block -> LDS-rank scatter. No hot global counters.
__global__ __launch_bounds__(256) void dfill_kernel(const int* __restrict__ deg,
                                                    int* __restrict__ dcur,
                                                    int* __restrict__ perm){
    __shared__ int cnt_[256], base_[256], rnk_[256];
    int tid = threadIdx.x;
    cnt_[tid] = 0; rnk_[tid] = 0;
    __syncthreads();
    for (int i = blockIdx.x * 256 + tid; i < NN; i += gridDim.x * 256){
        int d = deg[i]; d = d > 255 ? 255 : d;
        atomicAdd(&cnt_[d], 1);
    }
    __syncthreads();
    base_[tid] = cnt_[tid] ? atomicAdd(&dcur[tid], cnt_[tid]) : 0;
    __syncthreads();
    for (int i = blockIdx.x * 256 + tid; i < NN; i += gridDim.x * 256){
        int d = deg[i]; d = d > 255 ? 255 : d;
        int p = base_[d] + atomicAdd(&rnk_[d], 1);
        perm[p] = i;
    }
}

// ---------------- layer-weight prep: per-lane MFMA fragment layout, bf16 ----------------
__global__ __launch_bounds__(256) void wprep_kernel(const float* __restrict__ Wq,
        const float* __restrict__ Wk, const float* __restrict__ Wv,
        const float* __restrict__ Ws, u16* __restrict__ Wb2){
    int t = blockIdx.x * 256 + threadIdx.x;
    if (t >= 2 * 128 * 64) return;
    int lane = t & 63, fi = (t >> 6) & 127, l = t >> 13;
    int gnt = fi >> 2, kk = fi & 3;
    int m = gnt >> 3;
    int col = (gnt * 16 + (lane & 15)) & 127;
    const float* W = (m == 0 ? Wq : m == 1 ? Wk : m == 2 ? Wv : Ws) + (size_t)l * 16384;
    int k0 = kk * 32 + (lane >> 4) * 8;
    u16* dst = Wb2 + ((size_t)l * 128 + fi) * 512 + lane * 8;
    #pragma unroll
    for (int e = 0; e < 8; ++e) dst[e] = f2bf(W[(size_t)(k0 + e) * 128 + col]);
}

// ---------------- fused 4-matrix MFMA GEMM (16KB LDS, lazy fragments, direct stores) ----------------
// w=0 -> qb int8 x48; w=1 (k -> int8 x48), w=2 (v -> fp8) -> kvb (node row
// 256 B = 16 groups of 16 B {k_i8[8g..8g+7], v_fp8[8g..8g+7]});
// w=3 -> hsb = h + h@Ws + bs (bf16). Per-lane 4-col direct global stores.
__global__ __launch_bounds__(256, 8) void gemm4_mfma(const u16* __restrict__ hb,
        const u16* __restrict__ Wb2,
        const float* __restrict__ bq, const float* __restrict__ bk,
        const float* __restrict__ bv, const float* __restrict__ bs,
        u8* __restrict__ qb, u8* __restrict__ kvb, u16* __restrict__ hsb){
    __shared__ u16 hs[64 * 128];        // 16 KB, XOR-swizzled rows of 256B
    int tid = threadIdx.x;
    int n0  = blockIdx.x * 64;
    #pragma unroll
    for (int i = 0; i < 4; ++i){
        int c = i * 256 + tid;
        int row = c >> 4, cb = (c & 15) * 16;
        uint4 v = make_uint4(0u, 0u, 0u, 0u);
        if (n0 + row < NN)
            v = *reinterpret_cast<const uint4*>(hb + (size_t)(n0 + row) * 128 + cb / 2);
        *reinterpret_cast<uint4*>((char*)hs + row * 256 + (cb ^ ((row & 7) << 4))) = v;
    }
    __syncthreads();
    int l = tid & 63, w = tid >> 6;
    int r16 = l & 15, kq = l >> 4;
    const float* bp = w == 0 ? bq : w == 1 ? bk : w == 2 ? bv : bs;
    const short8* wfrag = reinterpret_cast<const short8*>(Wb2) + (size_t)(w * 8) * 4 * 64;
    for (int nt = 0; nt < 8; ++nt){
        f32x4 acc[4];
        #pragma unroll
        for (int rg = 0; rg < 4; ++rg) acc[rg] = (f32x4){0.f, 0.f, 0.f, 0.f};
        #pragma unroll
        for (int kk = 0; kk < 4; ++kk){
            short8 wf = wfrag[(nt * 4 + kk) * 64 + l];
            #pragma unroll
            for (int rg = 0; rg < 4; ++rg){
                int row = rg * 16 + r16;
                int byt = (kk * 64 + kq * 16) ^ ((row & 7) << 4);
                short8 hf = *reinterpret_cast<const short8*>(
                    (const char*)hs + row * 256 + byt);
                acc[rg] = __builtin_amdgcn_mfma_f32_16x16x32_bf16(wf, hf, acc[rg], 0, 0, 0);
            }
        }
        float4 bvv = *reinterpret_cast<const float4*>(bp + nt * 16 + kq * 4);
        #pragma unroll
        for (int rg = 0; rg < 4; ++rg){
            int row = rg * 16 + r16;
            if (n0 + row >= NN) continue;
            float a0 = acc[rg][0] + bvv.x, a1 = acc[rg][1] + bvv.y;
            float a2 = acc[rg][2] + bvv.z, a3 = acc[rg][3] + bvv.w;
            int col = nt * 16 + kq * 4;
            if (w == 0){            // q -> int8 (4B)
#ifdef USE_SDOT4
                *reinterpret_cast<u32*>(qb + (size_t)(n0 + row) * 128 + col)
                    = i8x4_enc(a0, a1, a2, a3);
#else
                *reinterpret_cast<uint2*>((u16*)qb + (size_t)(n0 + row) * 128 + col)
                    = make_uint2(pack2(a0, a1), pack2(a2, a3));
#endif
            } else if (w == 1){     // k -> int8 (or fp8 fallback) into kvb
                u32 pk;
#ifdef USE_SDOT4
                pk = i8x4_enc(a0, a1, a2, a3);
#else
                pk = fp8x4_enc(a0, a1, a2, a3);
#endif
                *reinterpret_cast<u32*>(kvb + (size_t)(n0 + row) * 256
                    + (col >> 3) * 16 + (col & 7)) = pk;
            } else if (w == 2){     // v -> fp8 into kvb (+8 within group)
                *reinterpret_cast<u32*>(kvb + (size_t)(n0 + row) * 256
                    + (col >> 3) * 16 + 8 + (col & 7)) = fp8x4_enc(a0, a1, a2, a3);
            } else {                // hsb = h + skip (bf16, 8B)
                int cb = (col * 2) ^ ((row & 7) << 4);
                uint2 hval = *reinterpret_cast<const uint2*>((const char*)hs + row * 256 + cb);
                a0 += bflo(hval.x); a1 += bfhi(hval.x);
                a2 += bflo(hval.y); a3 += bfhi(hval.y);
                *reinterpret_cast<uint2*>(hsb + (size_t)(n0 + row) * 128 + col)
                    = make_uint2(pack2(a0, a1), pack2(a2, a3));
            }
        }
    }
}

// ---------------- fused edge attention + aggregate + LN + ReLU ----------------
// 16-lane quarter owns ONE node (lane gq owns dims 8gq..8gq+7; head = gq>>2).
__global__ __launch_bounds__(256) void attn_kernel(u16* __restrict__ hb,
        const u8* __restrict__ qb, const u8* __restrict__ kvb,
        const u16* __restrict__ hsb,
        const int* __restrict__ offs, const int* __restrict__ deg,
        const int* __restrict__ ebuf, const int* __restrict__ perm,
        const float* __restrict__ gw, const float* __restrict__ bta){
    int tid = threadIdx.x;
    int gq  = tid & 15;
    int n   = perm[blockIdx.x * 16 + (tid >> 4)];
#ifdef USE_SDOT4
    uint2 qu = *reinterpret_cast<const uint2*>(qb + (size_t)n * 128 + gq * 8);
    int qi0 = (int)qu.x, qi1 = (int)qu.y;
#else
    const float scale = 0.17677669529663687f;
    uint4 qu = *reinterpret_cast<const uint4*>((const u16*)qb + (size_t)n * 128 + gq * 8);
    float q0 = bflo(qu.x) * scale, q1 = bfhi(qu.x) * scale;
    float q2 = bflo(qu.y) * scale, q3 = bfhi(qu.y) * scale;
    float q4 = bflo(qu.z) * scale, q5 = bfhi(qu.z) * scale;
    float q6 = bflo(qu.w) * scale, q7 = bfhi(qu.w) * scale;
#endif
    int beg = offs[n], cnt = deg[n];
    float z = 0.f;
    h2 acc01 = (h2)0, acc23 = (h2)0, acc45 = (h2)0, acc67 = (h2)0;
    const u8* kvg = kvb + gq * 16;     // per-lane gather base

#ifdef USE_SDOT4
    #define SCORE(kv)                                                                 \
        float s;                                                                      \
        {   int si = __builtin_amdgcn_sdot4((int)kv.x, qi0, 0, false);                \
            si = __builtin_amdgcn_sdot4((int)kv.y, qi1, si, false);                   \
            s = (float)si * DESCALE2; }
#else
    #define SCORE(kv)                                                                 \
        float s;                                                                      \
        {   float k0,k1,k2,k3,k4,k5,k6,k7;                                            \
            fp8x4_dec(kv.x, k0, k1, k2, k3); fp8x4_dec(kv.y, k4, k5, k6, k7);         \
            s = q0*k0 + q1*k1 + q2*k2 + q3*k3 + q4*k4 + q5*k5 + q6*k6 + q7*k7;        \
            s *= 1.4426950408889634f; }
#endif

    #define CONSUME(kv)                                                               \
    {   SCORE(kv);                                                                    \
        s += __shfl_xor(s, 1); s += __shfl_xor(s, 2);                                 \
        float ex = exp2f(s);                                                          \
        h2 v01, v23, v45, v67;                                                        \
        fp8x4_to_h2(kv.z, v01, v23);                                                  \
        fp8x4_to_h2(kv.w, v45, v67);                                                  \
        z += ex;                                                                      \
        _Float16 exh = (_Float16)ex;                                                  \
        h2 exv = {exh, exh};                                                          \
        acc01 = __builtin_elementwise_fma(exv, v01, acc01);                           \
        acc23 = __builtin_elementwise_fma(exv, v23, acc23);                           \
        acc45 = __builtin_elementwise_fma(exv, v45, acc45);                           \
        acc67 = __builtin_elementwise_fma(exv, v67, acc67);  }

    #define GATHER(off_) (*reinterpret_cast<const uint4*>(kvg + (size_t)(u32)(off_)))

    if (cnt > 0){
        uint4 kv = GATHER(ebuf[beg]);
        for (int t = 1; t < cnt; ++t){
            uint4 nk = GATHER(ebuf[beg + t]);   // issue next before consuming current
            CONSUME(kv);
            kv = nk;
        }
        CONSUME(kv);
    }
    #undef CONSUME
    #undef GATHER
    #undef SCORE

    float rz = (cnt > 0) ? 1.f / z : 0.f;      // z is per-head (replicated in 4-lane group)
    float a0 = (float)acc01[0], a1 = (float)acc01[1];
    float a2 = (float)acc23[0], a3 = (float)acc23[1];
    float a4 = (float)acc45[0], a5 = (float)acc45[1];
    float a6 = (float)acc67[0], a7 = (float)acc67[1];

    size_t p = (size_t)n * 128 + gq * 8;
    uint4 hu = *reinterpret_cast<const uint4*>(hsb + p);   // h + skip prefused
    float y0 = bflo(hu.x) + a0 * rz, y1 = bfhi(hu.x) + a1 * rz;
    float y2 = bflo(hu.y) + a2 * rz, y3 = bfhi(hu.y) + a3 * rz;
    float y4 = bflo(hu.z) + a4 * rz, y5 = bfhi(hu.z) + a5 * rz;
    float y6 = bflo(hu.w) + a6 * rz, y7 = bfhi(hu.w) + a7 * rz;
    float sum = y0 + y1 + y2 + y3 + y4 + y5 + y6 + y7;
    float sq  = y0*y0 + y1*y1 + y2*y2 + y3*y3 + y4*y4 + y5*y5 + y6*y6 + y7*y7;
    #pragma unroll
    for (int m = 1; m < 16; m <<= 1){        // quarter's 16 lanes hold all 128 dims
        sum += __shfl_xor(sum, m);
        sq  += __shfl_xor(sq,  m);
    }
    float mu  = sum * (1.f / 128.f);
    float var = sq * (1.f / 128.f) - mu * mu;
    var = var < 0.f ? 0.f : var;
    float inv = rsqrtf(var + 1e-5f);
    int c = gq * 8;
    float4 gm0 = *reinterpret_cast<const float4*>(gw + c);
    float4 gm1 = *reinterpret_cast<const float4*>(gw + c + 4);
    float4 bt0 = *reinterpret_cast<const float4*>(bta + c);
    float4 bt1 = *reinterpret_cast<const float4*>(bta + c + 4);
    float o0 = fmaf(gm0.x * (y0 - mu), inv, bt0.x);
    float o1 = fmaf(gm0.y * (y1 - mu), inv, bt0.y);
    float o2 = fmaf(gm0.z * (y2 - mu), inv, bt0.z);
    float o3 = fmaf(gm0.w * (y3 - mu), inv, bt0.w);
    float o4 = fmaf(gm1.x * (y4 - mu), inv, bt1.x);
    float o5 = fmaf(gm1.y * (y5 - mu), inv, bt1.y);
    float o6 = fmaf(gm1.z * (y6 - mu), inv, bt1.z);
    float o7 = fmaf(gm1.w * (y7 - mu), inv, bt1.w);
    o0 = o0 > 0.f ? o0 : 0.f;  o1 = o1 > 0.f ? o1 : 0.f;
    o2 = o2 > 0.f ? o2 : 0.f;  o3 = o3 > 0.f ? o3 : 0.f;
    o4 = o4 > 0.f ? o4 : 0.f;  o5 = o5 > 0.f ? o5 : 0.f;
    o6 = o6 > 0.f ? o6 : 0.f;  o7 = o7 > 0.f ? o7 : 0.f;
    *reinterpret_cast<uint4*>(hb + p) = make_uint4(
        pack2(o0, o1), pack2(o2, o3), pack2(o4, o5), pack2(o6, o7));
}

// ---------------- link prediction: sigmoid(h[src] . h[dst]) (bf16) ----------------
__global__ __launch_bounds__(256) void pair_kernel(const u16* __restrict__ hb,
                                                   const int* __restrict__ src,
                                                   const int* __restrict__ dst,
                                                   float* __restrict__ out){
    int tid = threadIdx.x;
    int pid = blockIdx.x * 16 + (tid >> 4);
    int sub = tid & 15;
    int s = src[pid], d = dst[pid];
    uint4 a = *reinterpret_cast<const uint4*>(hb + (size_t)s * 128 + sub * 8);
    uint4 b = *reinterpret_cast<const uint4*>(hb + (size_t)d * 128 + sub * 8);
    float dot = bflo(a.x) * bflo(b.x) + bfhi(a.x) * bfhi(b.x)
              + bflo(a.y) * bflo(b.y) + bfhi(a.y) * bfhi(b.y)
              + bflo(a.z) * bflo(b.z) + bfhi(a.z) * bfhi(b.z)
              + bflo(a.w) * bflo(b.w) + bfhi(a.w) * bfhi(b.w);
    dot += __shfl_xor(dot, 1); dot += __shfl_xor(dot, 2);
    dot += __shfl_xor(dot, 4); dot += __shfl_xor(dot, 8);
    if (sub == 0) out[pid] = 1.f / (1.f + __expf(-dot));
}

extern "C" void kernel_launch(void* const* d_in, const int* in_sizes, int n_in,
                              void* d_out, int out_size, void* d_ws, size_t ws_size,
                              hipStream_t stream){
    const float* x      = (const float*)d_in[0];
    const float* rw     = (const float*)d_in[1];
    const int*   ei     = (const int*)  d_in[2];
    const int*   src    = (const int*)  d_in[3];
    const int*   dst    = (const int*)  d_in[4];
    const float* W_rwse = (const float*)d_in[5];
    const float* b_rwse = (const float*)d_in[6];
    const float* W_in   = (const float*)d_in[7];
    const float* b_in   = (const float*)d_in[8];
    const float* Wq     = (const float*)d_in[9];
    const float* bq     = (const float*)d_in[10];
    const float* Wk     = (const float*)d_in[11];
    const float* bk     = (const float*)d_in[12];
    const float* Wv     = (const float*)d_in[13];
    const float* bv     = (const float*)d_in[14];
    const float* Wsk    = (const float*)d_in[15];
    const float* bsk    = (const float*)d_in[16];
    const float* ln_g   = (const float*)d_in[17];
    const float* ln_b   = (const float*)d_in[18];
    float* out = (float*)d_out;

    char* p = (char*)d_ws;
    auto carve = [&](size_t bytes) -> char* {
        char* r = p; p += (bytes + 255) & ~(size_t)255; return r;
    };
    u16*   hb    = (u16*) carve((size_t)NN * 128 * 2);   // 25.6 MB
    u8*    qb    = (u8*)  carve((size_t)NN * 128 * 2);   // int8 (or bf16 fallback)
    u8*    kvb   = (u8*)  carve((size_t)NN * 256);       // 25.6 MB int8 k | fp8 v
    u16*   hsb   = (u16*) carve((size_t)NN * 128 * 2);   // h + skip prefused
    int*   offs  = (int*) carve((size_t)NN * 4);
    int*   deg   = (int*) carve((size_t)NN * 4);
    int*   ebuf  = (int*) carve((size_t)EE * 4);         // 4 MB (byte offsets)
    u32*   bkt   = (u32*) carve((size_t)EE * 4);         // 4 MB packed records
    int*   bcnt  = (int*) carve((size_t)BKT * 4);
    int*   bstart= (int*) carve((size_t)BKT * 4);
    int*   bwork = (int*) carve((size_t)BKT * 4);
    int*   perm  = (int*) carve((size_t)NN * 4);
    int*   dh    = (int*) carve((size_t)256 * 4);
    int*   dcur  = (int*) carve((size_t)256 * 4);
    u16*   Wb2   = (u16*) carve((size_t)2 * 128 * 512 * 2);  // 256 KB
    u16*   Winb  = (u16*) carve((size_t)8 * 5 * 512 * 2);    //  40 KB

    hipMemsetAsync(bcnt, 0, (size_t)BKT * 4, stream);
    hipMemsetAsync(dh, 0, (size_t)256 * 4, stream);

    winprep_kernel<<<10, 256, 0, stream>>>(W_in, Winb);
    wprep_kernel<<<64, 256, 0, stream>>>(Wq, Wk, Wv, Wsk, Wb2);
    inproj_mfma<<<(NN + 63) / 64, 512, 0, stream>>>(x, rw, W_rwse, b_rwse,
                                                    Winb, b_in, hb);
    bhist_kernel<<<512, 256, 0, stream>>>(ei + EE, bcnt);
    bscan_kernel<<<1, 256, 0, stream>>>(bcnt, bstart, bwork);
    bpart_kernel<<<512, 256, 0, stream>>>(ei, bwork, bkt);
    bcsr_kernel<<<BKT, 256, 0, stream>>>(bstart, bcnt, bkt, offs, deg, ebuf);
    dhist_kernel<<<256, 256, 0, stream>>>(deg, dh);
    dscan_kernel<<<1, 256, 0, stream>>>(dh, dcur);
    dfill_kernel<<<256, 256, 0, stream>>>(deg, dcur, perm);

    for (int l = 0; l < 2; ++l){
        gemm4_mfma<<<(NN + 63) / 64, 256, 0, stream>>>(hb, Wb2 + (size_t)l * 65536,
            bq + l * 128, bk + l * 128, bv + l * 128, bsk + l * 128,
            qb, kvb, hsb);
        attn_kernel<<<NN / 16, 256, 0, stream>>>(hb, qb, kvb, hsb,
            offs, deg, ebuf, perm, ln_g + l * 128, ln_b + l * 128);
    }
    pair_kernel<<<NPAIRSC / 16, 256, 0, stream>>>(hb, src, dst, out);
}

// Round 18
// 279.652 us; speedup vs baseline: 1.9339x; 1.9339x over previous
//
#include <hip/hip_runtime.h>
#include <hip/hip_bf16.h>
#include <cstdint>

// GraphTransformerLinkPredictor on MI355X.
// bf16-canonical h. fused MFMA input proj (512-thread, lazy ds_read, direct
// stores) -> bucketed CSR build + degree-sorted perm -> 2x { gemm4 MFMA bf16
// (512-thread, 2 waves/matrix, ob repack -> coalesced full-row stores:
// q int8, k int8 + v fp8 kvb, hsb = h + skip) -> fused edge attn+LN (16-lane
// quarter owns one node; sdot4 score; packed-fp16 v accum; kv pipeline) }
// -> pair dot (bf16).
// Softmax identity: alpha = exp(s)/sum(exp(s)) (scores bounded, no max pass).

#define NN      100000
#define EE      1000000
#define RWSEC   16
#define WALKC   16
#define NPAIRSC 200000
#define BSH     9                       // 512 nodes per bucket
#define BKT     ((NN + 511) >> BSH)     // 196

typedef unsigned int       u32;
typedef unsigned short     u16;
typedef unsigned char      u8;
typedef __attribute__((ext_vector_type(8))) short    short8;
typedef __attribute__((ext_vector_type(4))) float    f32x4;
typedef __attribute__((ext_vector_type(2))) _Float16 h2;

__device__ __forceinline__ float bflo(u32 u){ return __uint_as_float(u << 16); }
__device__ __forceinline__ float bfhi(u32 u){ return __uint_as_float(u & 0xffff0000u); }
__device__ __forceinline__ u16 f2bf(float f){
    u32 u = __float_as_uint(f);
    u += 0x7fffu + ((u >> 16) & 1u);   // round-to-nearest-even
    return (u16)(u >> 16);
}
__device__ __forceinline__ u32 pack2(float a, float b){
    return (u32)f2bf(a) | ((u32)f2bf(b) << 16);
}

// ---- fp8 e4m3 + int8 helpers (HW cvt on gfx950; manual fallback) ----
#if defined(__has_builtin)
#if __has_builtin(__builtin_amdgcn_cvt_pk_f32_fp8) && __has_builtin(__builtin_amdgcn_cvt_pk_fp8_f32)
#define HWFP8 1
#endif
#if __has_builtin(__builtin_amdgcn_sdot4)
#define USE_SDOT4 1
#endif
#if __has_builtin(__builtin_amdgcn_cvt_pk_f16_fp8)
#define HWF16FP8 1
#endif
#endif

#ifndef HWFP8
__device__ __forceinline__ float fp8dec1(u32 b){
    u32 s = (b >> 7) & 1u, e = (b >> 3) & 15u, m = b & 7u;
    float mag = e ? __uint_as_float(((e + 120u) << 23) | (m << 20))
                  : (float)m * 0.001953125f;
    return s ? -mag : mag;
}
__device__ __forceinline__ u32 fp8enc1(float f){
    u32 u = __float_as_uint(f); u32 s = (u >> 31) << 7; float a = fabsf(f);
    if (a >= 448.f) return s | 0x7Eu;
    u32 ua = __float_as_uint(a);
    ua += 0x7FFFFu + ((ua >> 20) & 1u);
    int e = (int)(ua >> 23) - 127 + 7;
    if (e <= 0){ int m = (int)rintf(a * 512.f); return s | (u32)m; }
    u32 m = (ua >> 20) & 7u;
    return s | ((u32)e << 3) | m;
}
#endif

__device__ __forceinline__ void fp8x4_dec(u32 w4, float& f0, float& f1, float& f2, float& f3){
#ifdef HWFP8
    auto lo = __builtin_amdgcn_cvt_pk_f32_fp8((int)w4, false);
    auto hi = __builtin_amdgcn_cvt_pk_f32_fp8((int)w4, true);
    f0 = lo[0]; f1 = lo[1]; f2 = hi[0]; f3 = hi[1];
#else
    f0 = fp8dec1(w4 & 255u); f1 = fp8dec1((w4 >> 8) & 255u);
    f2 = fp8dec1((w4 >> 16) & 255u); f3 = fp8dec1(w4 >> 24);
#endif
}
__device__ __forceinline__ u32 fp8x4_enc(float f0, float f1, float f2, float f3){
#ifdef HWFP8
    u32 t = (u32)__builtin_amdgcn_cvt_pk_fp8_f32(f0, f1, 0, false);
    return (u32)__builtin_amdgcn_cvt_pk_fp8_f32(f2, f3, (int)t, true);
#else
    return fp8enc1(f0) | (fp8enc1(f1) << 8) | (fp8enc1(f2) << 16) | (fp8enc1(f3) << 24);
#endif
}
// decode 4 fp8 -> 2 packed half2 (bit_cast: pkrtz returns __fp16x2, same layout)
__device__ __forceinline__ void fp8x4_to_h2(u32 w, h2& lo, h2& hi){
#ifdef HWF16FP8
    lo = __builtin_bit_cast(h2, __builtin_amdgcn_cvt_pk_f16_fp8((int)w, false));
    hi = __builtin_bit_cast(h2, __builtin_amdgcn_cvt_pk_f16_fp8((int)w, true));
#else
    float f0, f1, f2, f3;
    fp8x4_dec(w, f0, f1, f2, f3);
    lo = __builtin_bit_cast(h2, __builtin_amdgcn_cvt_pkrtz(f0, f1));
    hi = __builtin_bit_cast(h2, __builtin_amdgcn_cvt_pkrtz(f2, f3));
#endif
}

#define QSCALE    48.0f
#define DESCALE2  1.10693e-4f           // log2(e)/(48*48*sqrt(32))

__device__ __forceinline__ int i8q(float f){
    float c = fminf(fmaxf(f * QSCALE, -127.f), 127.f);
    return (int)rintf(c);
}
__device__ __forceinline__ u32 i8x4_enc(float f0, float f1, float f2, float f3){
    return (u32)(i8q(f0) & 255) | ((u32)(i8q(f1) & 255) << 8)
         | ((u32)(i8q(f2) & 255) << 16) | ((u32)(i8q(f3) & 255) << 24);
}
__device__ __forceinline__ float sb(u32 w, int i){
    return (float)(int)(signed char)((w >> (i * 8)) & 255u);
}

// ---------------- W_in prep: per-lane MFMA fragments, K padded 144->160 ----------------
__global__ __launch_bounds__(256) void winprep_kernel(const float* __restrict__ Win,
                                                      u16* __restrict__ Winb){
    int t = blockIdx.x * 256 + threadIdx.x;
    if (t >= 8 * 5 * 64) return;
    int lane = t & 63, fi = t >> 6;          // fi = nt*5+kk
    int nt = fi / 5, kk = fi - nt * 5;
    int col = nt * 16 + (lane & 15);
    int k0  = kk * 32 + (lane >> 4) * 8;
    u16* dst = Winb + (size_t)fi * 512 + lane * 8;
    #pragma unroll
    for (int e = 0; e < 8; ++e){
        int k = k0 + e;
        dst[e] = (k < 144) ? f2bf(Win[(size_t)k * 128 + col]) : (u16)0;
    }
}

// ---------------- fused input proj (MFMA): hb = bf16(concat(x, rw@Wr+br) @ W_in + b_in) ----------------
__global__ __launch_bounds__(512, 8) void inproj_mfma(const float* __restrict__ x,
        const float* __restrict__ rw, const float* __restrict__ Wr,
        const float* __restrict__ br,
        const u16* __restrict__ Winb, const float* __restrict__ bin,
        u16* __restrict__ hb){
    __shared__ u16   hs[64 * 168];     // row stride 336 B, cols 0..159
    __shared__ float rws[64 * 16];
    int tid = threadIdx.x;
    int n0  = blockIdx.x * 64;

    #pragma unroll
    for (int i = 0; i < 4; ++i){
        int g   = i * 512 + tid;
        int row = g >> 5, c4 = g & 31;
        float4 f = make_float4(0.f, 0.f, 0.f, 0.f);
        if (n0 + row < NN)
            f = *reinterpret_cast<const float4*>(x + (size_t)(n0 + row) * 128 + c4 * 4);
        *reinterpret_cast<uint2*>((char*)hs + row * 336 + c4 * 8)
            = make_uint2(pack2(f.x, f.y), pack2(f.z, f.w));
    }
    if (tid < 256){
        int row = tid >> 2, c4 = tid & 3;
        float4 f = make_float4(0.f, 0.f, 0.f, 0.f);
        if (n0 + row < NN)
            f = *reinterpret_cast<const float4*>(rw + (size_t)(n0 + row) * 16 + c4 * 4);
        *reinterpret_cast<float4*>(&rws[row * 16 + c4 * 4]) = f;
    }
    __syncthreads();
    if (tid < 256){
        int row = tid >> 2, j0 = (tid & 3) * 4;
        float p0 = br[j0], p1 = br[j0 + 1], p2 = br[j0 + 2], p3 = br[j0 + 3];
        #pragma unroll
        for (int w = 0; w < 16; ++w){
            float r = rws[row * 16 + w];
            const float4 wv = *reinterpret_cast<const float4*>(Wr + w * 16 + j0);
            p0 = fmaf(r, wv.x, p0); p1 = fmaf(r, wv.y, p1);
            p2 = fmaf(r, wv.z, p2); p3 = fmaf(r, wv.w, p3);
        }
        *reinterpret_cast<uint2*>((char*)hs + row * 336 + 256 + (tid & 3) * 8)
            = make_uint2(pack2(p0, p1), pack2(p2, p3));
        *reinterpret_cast<uint2*>((char*)hs + row * 336 + 288 + (tid & 3) * 8)
            = make_uint2(0u, 0u);
    }
    __syncthreads();

    int l = tid & 63, w = tid >> 6;    // wave w owns nt = w
    int r16 = l & 15, kq = l >> 4;
    const short8* wfrag = reinterpret_cast<const short8*>(Winb) + (size_t)(w * 5) * 64;
    f32x4 acc[4];
    #pragma unroll
    for (int rg = 0; rg < 4; ++rg) acc[rg] = (f32x4){0.f, 0.f, 0.f, 0.f};
    for (int kk = 0; kk < 5; ++kk){
        short8 wf = wfrag[kk * 64 + l];
        #pragma unroll
        for (int rg = 0; rg < 4; ++rg){
            int row = rg * 16 + r16;
            short8 hf = *reinterpret_cast<const short8*>(
                (const char*)hs + row * 336 + kk * 64 + kq * 16);
            acc[rg] = __builtin_amdgcn_mfma_f32_16x16x32_bf16(wf, hf, acc[rg], 0, 0, 0);
        }
    }
    float4 bv = *reinterpret_cast<const float4*>(bin + w * 16 + kq * 4);
    #pragma unroll
    for (int rg = 0; rg < 4; ++rg){
        int row = rg * 16 + r16;
        if (n0 + row < NN){
            u32 lo = pack2(acc[rg][0] + bv.x, acc[rg][1] + bv.y);
            u32 hi = pack2(acc[rg][2] + bv.z, acc[rg][3] + bv.w);
            *reinterpret_cast<uint2*>(hb + (size_t)(n0 + row) * 128 + w * 16 + kq * 4)
                = make_uint2(lo, hi);
        }
    }
}

// ---------------- bucketed CSR build (u32-packed records) ----------------
__global__ __launch_bounds__(256) void bhist_kernel(const int* __restrict__ col,
                                                    int* __restrict__ bcnt){
    __shared__ int h[BKT];
    int tid = threadIdx.x;
    for (int i = tid; i < BKT; i += 256) h[i] = 0;
    __syncthreads();
    for (int e = blockIdx.x * 256 + tid; e < EE; e += gridDim.x * 256)
        atomicAdd(&h[col[e] >> BSH], 1);
    __syncthreads();
    for (int i = tid; i < BKT; i += 256)
        if (h[i]) atomicAdd(&bcnt[i], h[i]);
}

__global__ __launch_bounds__(256) void bscan_kernel(const int* __restrict__ bcnt,
                                                    int* __restrict__ bstart,
                                                    int* __restrict__ bwork){
    __shared__ int lds[256];
    int tid = threadIdx.x;
    int v = (tid < BKT) ? bcnt[tid] : 0;
    lds[tid] = v;
    __syncthreads();
    for (int off = 1; off < 256; off <<= 1){
        int y = (tid >= off) ? lds[tid - off] : 0;
        __syncthreads();
        lds[tid] += y;
        __syncthreads();
    }
    if (tid < BKT){ int p = lds[tid] - v; bstart[tid] = p; bwork[tid] = p; }
}

__global__ __launch_bounds__(256) void bpart_kernel(const int* __restrict__ ei,
                                                    int* __restrict__ bwork,
                                                    u32* __restrict__ bkt){
    __shared__ int cnt_[BKT], base_[BKT], rnk_[BKT];
    int tid = threadIdx.x;
    for (int i = tid; i < BKT; i += 256){ cnt_[i] = 0; rnk_[i] = 0; }
    __syncthreads();
    for (int e = blockIdx.x * 256 + tid; e < EE; e += gridDim.x * 256)
        atomicAdd(&cnt_[ei[EE + e] >> BSH], 1);
    __syncthreads();
    for (int i = tid; i < BKT; i += 256)
        base_[i] = cnt_[i] ? atomicAdd(&bwork[i], cnt_[i]) : 0;
    __syncthreads();
    for (int e = blockIdx.x * 256 + tid; e < EE; e += gridDim.x * 256){
        int c = ei[EE + e], b = c >> BSH;
        int p = base_[b] + atomicAdd(&rnk_[b], 1);
        bkt[p] = ((u32)ei[e] << BSH) | (u32)(c & 511);   // row(17b) | col-in-bucket(9b)
    }
}

// one block per bucket: build deg/offs/ebuf with LDS atomics + LDS scan
// ebuf stores BYTE offsets (r*256) for direct kvb addressing in attn.
__global__ __launch_bounds__(256) void bcsr_kernel(const int* __restrict__ bstart,
                                                   const int* __restrict__ bcnt,
                                                   const u32* __restrict__ bkt,
                                                   int* __restrict__ offs,
                                                   int* __restrict__ deg,
                                                   int* __restrict__ ebuf){
    __shared__ int dcnt[512];
    __shared__ int pref[512];
    __shared__ int psum[256];
    int b   = blockIdx.x;
    int tid = threadIdx.x;
    int n0  = b << BSH;
    int nb  = NN - n0 < 512 ? NN - n0 : 512;
    int e0  = bstart[b];
    int ec  = bcnt[b];
    dcnt[tid] = 0; dcnt[tid + 256] = 0;
    __syncthreads();
    for (int i = tid; i < ec; i += 256)
        atomicAdd(&dcnt[bkt[e0 + i] & 511u], 1);
    __syncthreads();
    int s0 = dcnt[2 * tid], s1 = dcnt[2 * tid + 1];
    psum[tid] = s0 + s1;
    __syncthreads();
    for (int off = 1; off < 256; off <<= 1){
        int y = (tid >= off) ? psum[tid - off] : 0;
        __syncthreads();
        psum[tid] += y;
        __syncthreads();
    }
    int exq = psum[tid] - (s0 + s1);
    pref[2 * tid]     = exq;
    pref[2 * tid + 1] = exq + s0;
    __syncthreads();
    for (int i = tid; i < nb; i += 256){
        offs[n0 + i] = e0 + pref[i];
        deg[n0 + i]  = dcnt[i];
    }
    __syncthreads();
    for (int i = tid; i < ec; i += 256){
        u32 rc = bkt[e0 + i];
        int p = atomicAdd(&pref[rc & 511u], 1);
        ebuf[e0 + p] = (int)((rc >> BSH) << 8);   // r * 256 byte offset
    }
}

// ---------------- degree-sorted node permutation (counting sort, 256 bins) ----------------
__global__ __launch_bounds__(256) void dhist_kernel(const int* __restrict__ deg,
                                                    int* __restrict__ dh){
    __shared__ int h[256];
    int tid = threadIdx.x;
    h[tid] = 0;
    __syncthreads();
    for (int i = blockIdx.x * 256 + tid; i < NN; i += gridDim.x * 256){
        int d = deg[i]; d = d > 255 ? 255 : d;
        atomicAdd(&h[d], 1);
    }
    __syncthreads();
    if (h[tid]) atomicAdd(&dh[tid], h[tid]);
}

__global__ __launch_bounds__(256) void dscan_kernel(const int* __restrict__ dh,
                                                    int* __restrict__ dcur){
    __shared__ int lds[256];
    int tid = threadIdx.x;
    int v = dh[tid];
    lds[tid] = v;
    __syncthreads();
    for (int off = 1; off < 256; off <<= 1){
        int y = (tid >= off) ? lds[tid - off] : 0;
        __syncthreads();
        lds[tid] += y;
        __syncthreads();
    }
    dcur[tid] = lds[tid] - v;
}

// block-reserved scatter (bpart pattern): LDS count -> one global reservation
// per populated bin per block -> LDS-rank scatter. No hot global counters.
__global__ __launch_bounds__(256) void dfill_kernel(const int* __restrict__ deg,
                                                    int* __restrict__ dcur,
                                                    int* __restrict__ perm){
    __shared__ int cnt_[256], base_[256], rnk_[256];
    int tid = threadIdx.x;
    cnt_[tid] = 0; rnk_[tid] = 0;
    __syncthreads();
    for (int i = blockIdx.x * 256 + tid; i < NN; i += gridDim.x * 256){
        int d = deg[i]; d = d > 255 ? 255 : d;
        atomicAdd(&cnt_[d], 1);
    }
    __syncthreads();
    base_[tid] = cnt_[tid] ? atomicAdd(&dcur[tid], cnt_[tid]) : 0;
    __syncthreads();
    for (int i = blockIdx.x * 256 + tid; i < NN; i += gridDim.x * 256){
        int d = deg[i]; d = d > 255 ? 255 : d;
        int p = base_[d] + atomicAdd(&rnk_[d], 1);
        perm[p] = i;
    }
}

// ---------------- layer-weight prep: per-lane MFMA fragment layout, bf16 ----------------
__global__ __launch_bounds__(256) void wprep_kernel(const float* __restrict__ Wq,
        const float* __restrict__ Wk, const float* __restrict__ Wv,
        const float* __restrict__ Ws, u16* __restrict__ Wb2){
    int t = blockIdx.x * 256 + threadIdx.x;
    if (t >= 2 * 128 * 64) return;
    int lane = t & 63, fi = (t >> 6) & 127, l = t >> 13;
    int gnt = fi >> 2, kk = fi & 3;
    int m = gnt >> 3;
    int col = (gnt * 16 + (lane & 15)) & 127;
    const float* W = (m == 0 ? Wq : m == 1 ? Wk : m == 2 ? Wv : Ws) + (size_t)l * 16384;
    int k0 = kk * 32 + (lane >> 4) * 8;
    u16* dst = Wb2 + ((size_t)l * 128 + fi) * 512 + lane * 8;
    #pragma unroll
    for (int e = 0; e < 8; ++e) dst[e] = f2bf(W[(size_t)(k0 + e) * 128 + col]);
}

// ---------------- fused 4-matrix MFMA GEMM (512 thr, 2 waves/matrix, ob repack) ----------------
// wave w: matrix m = w>>1, row-half rh = w&1 (rows rh*32..rh*32+31).
// m=0 -> qb int8 x48; m=1 (k int8), m=2 (v fp8) -> kvb 16B-group rows;
// m=3 -> hsb = h + h@Ws + bs (bf16). ob repack -> coalesced full-row stores.
__global__ __launch_bounds__(512, 4) void gemm4_mfma(const u16* __restrict__ hb,
        const u16* __restrict__ Wb2,
        const float* __restrict__ bq, const float* __restrict__ bk,
        const float* __restrict__ bv, const float* __restrict__ bs,
        u8* __restrict__ qb, u8* __restrict__ kvb, u16* __restrict__ hsb){
    __shared__ u16 hs[64 * 128];        // 16 KB, XOR-swizzled rows of 256B
    __shared__ u16 ob[4][64 * 128];     // 64 KB, per-matrix repack buffers
    int tid = threadIdx.x;
    int n0  = blockIdx.x * 64;
    #pragma unroll
    for (int i = 0; i < 2; ++i){
        int c = i * 512 + tid;
        int row = c >> 4, cb = (c & 15) * 16;
        uint4 v = make_uint4(0u, 0u, 0u, 0u);
        if (n0 + row < NN)
            v = *reinterpret_cast<const uint4*>(hb + (size_t)(n0 + row) * 128 + cb / 2);
        *reinterpret_cast<uint4*>((char*)hs + row * 256 + (cb ^ ((row & 7) << 4))) = v;
    }
    __syncthreads();
    int l = tid & 63, w = tid >> 6;
    int m = w >> 1, rh = w & 1;
    int r16 = l & 15, kq = l >> 4;
    short8 ha[2][4];
    #pragma unroll
    for (int g = 0; g < 2; ++g)
        #pragma unroll
        for (int kk = 0; kk < 4; ++kk){
            int row = (rh * 2 + g) * 16 + r16;
            int byt = (kk * 64 + kq * 16) ^ ((row & 7) << 4);
            ha[g][kk] = *reinterpret_cast<const short8*>((const char*)hs + row * 256 + byt);
        }
    const float* bp = m == 0 ? bq : m == 1 ? bk : m == 2 ? bv : bs;
    const short8* wfrag = reinterpret_cast<const short8*>(Wb2) + (size_t)(m * 8) * 4 * 64;
    u16* myob = &ob[m][0];
    #pragma unroll
    for (int nt = 0; nt < 8; ++nt){
        f32x4 acc[2];
        acc[0] = (f32x4){0.f, 0.f, 0.f, 0.f};
        acc[1] = (f32x4){0.f, 0.f, 0.f, 0.f};
        #pragma unroll
        for (int kk = 0; kk < 4; ++kk){
            short8 wf = wfrag[(nt * 4 + kk) * 64 + l];
            acc[0] = __builtin_amdgcn_mfma_f32_16x16x32_bf16(wf, ha[0][kk], acc[0], 0, 0, 0);
            acc[1] = __builtin_amdgcn_mfma_f32_16x16x32_bf16(wf, ha[1][kk], acc[1], 0, 0, 0);
        }
        float4 bvv = *reinterpret_cast<const float4*>(bp + nt * 16 + kq * 4);
        #pragma unroll
        for (int g = 0; g < 2; ++g){
            int row = (rh * 2 + g) * 16 + r16;
            int cb  = (nt * 32 + kq * 8) ^ ((row & 7) << 4);
            float a0 = acc[g][0] + bvv.x, a1 = acc[g][1] + bvv.y;
            float a2 = acc[g][2] + bvv.z, a3 = acc[g][3] + bvv.w;
            if (m == 3){   // fuse residual: h at same swizzled addr
                uint2 hval = *reinterpret_cast<const uint2*>((const char*)hs + row * 256 + cb);
                a0 += bflo(hval.x); a1 += bfhi(hval.x);
                a2 += bflo(hval.y); a3 += bfhi(hval.y);
            }
            *reinterpret_cast<uint2*>((char*)myob + row * 256 + cb)
                = make_uint2(pack2(a0, a1), pack2(a2, a3));
        }
    }
    asm volatile("s_waitcnt lgkmcnt(0)" ::: "memory");
    // wave-local epilogue: repack own 32 rows, coalesced full-row stores
    if (m == 1 || m == 2){
        int off = (m == 2) ? 8 : 0;     // byte offset of v-half within 16B group
        #pragma unroll
        for (int i = 0; i < 8; ++i){
            int row = rh * 32 + i * 4 + kq;
            int cb  = r16 * 16;
            uint4 v = *reinterpret_cast<const uint4*>(
                (char*)myob + row * 256 + (cb ^ ((row & 7) << 4)));
            if (n0 + row < NN){
                u32 A, B;
#ifdef USE_SDOT4
                if (m == 1){   // k: int8 x QSCALE
                    A = i8x4_enc(bflo(v.x), bfhi(v.x), bflo(v.y), bfhi(v.y));
                    B = i8x4_enc(bflo(v.z), bfhi(v.z), bflo(v.w), bfhi(v.w));
                } else
#endif
                {
                    A = fp8x4_enc(bflo(v.x), bfhi(v.x), bflo(v.y), bfhi(v.y));
                    B = fp8x4_enc(bflo(v.z), bfhi(v.z), bflo(v.w), bfhi(v.w));
                }
                *reinterpret_cast<uint2*>((char*)kvb + (size_t)(n0 + row) * 256
                                          + r16 * 16 + off) = make_uint2(A, B);
            }
        }
    } else if (m == 0){   // q -> int8 (x48), 128 B per node
        #pragma unroll
        for (int i = 0; i < 8; ++i){
            int row = rh * 32 + i * 4 + kq;
            int cb  = r16 * 16;
            uint4 v = *reinterpret_cast<const uint4*>(
                (char*)myob + row * 256 + (cb ^ ((row & 7) << 4)));
            if (n0 + row < NN){
#ifdef USE_SDOT4
                u32 A = i8x4_enc(bflo(v.x), bfhi(v.x), bflo(v.y), bfhi(v.y));
                u32 B = i8x4_enc(bflo(v.z), bfhi(v.z), bflo(v.w), bfhi(v.w));
                *reinterpret_cast<uint2*>(qb + (size_t)(n0 + row) * 128 + cb / 2)
                    = make_uint2(A, B);
#else
                *reinterpret_cast<uint4*>((u16*)qb + (size_t)(n0 + row) * 128 + cb / 2) = v;
#endif
            }
        }
    } else {
        #pragma unroll
        for (int i = 0; i < 8; ++i){
            int row = rh * 32 + i * 4 + kq;
            int cb  = r16 * 16;
            uint4 v = *reinterpret_cast<const uint4*>(
                (char*)myob + row * 256 + (cb ^ ((row & 7) << 4)));
            if (n0 + row < NN)
                *reinterpret_cast<uint4*>(hsb + (size_t)(n0 + row) * 128 + cb / 2) = v;
        }
    }
}

// ---------------- fused edge attention + aggregate + LN + ReLU ----------------
// 16-lane quarter owns ONE node (lane gq owns dims 8gq..8gq+7; head = gq>>2).
__global__ __launch_bounds__(256) void attn_kernel(u16* __restrict__ hb,
        const u8* __restrict__ qb, const u8* __restrict__ kvb,
        const u16* __restrict__ hsb,
        const int* __restrict__ offs, const int* __restrict__ deg,
        const int* __restrict__ ebuf, const int* __restrict__ perm,
        const float* __restrict__ gw, const float* __restrict__ bta){
    int tid = threadIdx.x;
    int gq  = tid & 15;
    int n   = perm[blockIdx.x * 16 + (tid >> 4)];
#ifdef USE_SDOT4
    uint2 qu = *reinterpret_cast<const uint2*>(qb + (size_t)n * 128 + gq * 8);
    int qi0 = (int)qu.x, qi1 = (int)qu.y;
#else
    const float scale = 0.17677669529663687f;
    uint4 qu = *reinterpret_cast<const uint4*>((const u16*)qb + (size_t)n * 128 + gq * 8);
    float q0 = bflo(qu.x) * scale, q1 = bfhi(qu.x) * scale;
    float q2 = bflo(qu.y) * scale, q3 = bfhi(qu.y) * scale;
    float q4 = bflo(qu.z) * scale, q5 = bfhi(qu.z) * scale;
    float q6 = bflo(qu.w) * scale, q7 = bfhi(qu.w) * scale;
#endif
    int beg = offs[n], cnt = deg[n];
    float z = 0.f;
    h2 acc01 = (h2)0, acc23 = (h2)0, acc45 = (h2)0, acc67 = (h2)0;
    const u8* kvg = kvb + gq * 16;     // per-lane gather base

#ifdef USE_SDOT4
    #define SCORE(kv)                                                                 \
        float s;                                                                      \
        {   int si = __builtin_amdgcn_sdot4((int)kv.x, qi0, 0, false);                \
            si = __builtin_amdgcn_sdot4((int)kv.y, qi1, si, false);                   \
            s = (float)si * DESCALE2; }
#else
    #define SCORE(kv)                                                                 \
        float s;                                                                      \
        {   float k0,k1,k2,k3,k4,k5,k6,k7;                                            \
            fp8x4_dec(kv.x, k0, k1, k2, k3); fp8x4_dec(kv.y, k4, k5, k6, k7);         \
            s = q0*k0 + q1*k1 + q2*k2 + q3*k3 + q4*k4 + q5*k5 + q6*k6 + q7*k7;        \
            s *= 1.4426950408889634f; }
#endif

    #define CONSUME(kv)                                                               \
    {   SCORE(kv);                                                                    \
        s += __shfl_xor(s, 1); s += __shfl_xor(s, 2);                                 \
        float ex = exp2f(s);                                                          \
        h2 v01, v23, v45, v67;                                                        \
        fp8x4_to_h2(kv.z, v01, v23);                                                  \
        fp8x4_to_h2(kv.w, v45, v67);                                                  \
        z += ex;                                                                      \
        _Float16 exh = (_Float16)ex;                                                  \
        h2 exv = {exh, exh};                                                          \
        acc01 = __builtin_elementwise_fma(exv, v01, acc01);                           \
        acc23 = __builtin_elementwise_fma(exv, v23, acc23);                           \
        acc45 = __builtin_elementwise_fma(exv, v45, acc45);                           \
        acc67 = __builtin_elementwise_fma(exv, v67, acc67);  }

    #define GATHER(off_) (*reinterpret_cast<const uint4*>(kvg + (size_t)(u32)(off_)))

    if (cnt > 0){
        uint4 kv = GATHER(ebuf[beg]);
        for (int t = 1; t < cnt; ++t){
            uint4 nk = GATHER(ebuf[beg + t]);   // issue next before consuming current
            CONSUME(kv);
            kv = nk;
        }
        CONSUME(kv);
    }
    #undef CONSUME
    #undef GATHER
    #undef SCORE

    float rz = (cnt > 0) ? 1.f / z : 0.f;      // z is per-head (replicated in 4-lane group)
    float a0 = (float)acc01[0], a1 = (float)acc01[1];
    float a2 = (float)acc23[0], a3 = (float)acc23[1];
    float a4 = (float)acc45[0], a5 = (float)acc45[1];
    float a6 = (float)acc67[0], a7 = (float)acc67[1];

    size_t p = (size_t)n * 128 + gq * 8;
    uint4 hu = *reinterpret_cast<const uint4*>(hsb + p);   // h + skip prefused
    float y0 = bflo(hu.x) + a0 * rz, y1 = bfhi(hu.x) + a1 * rz;
    float y2 = bflo(hu.y) + a2 * rz, y3 = bfhi(hu.y) + a3 * rz;
    float y4 = bflo(hu.z) + a4 * rz, y5 = bfhi(hu.z) + a5 * rz;
    float y6 = bflo(hu.w) + a6 * rz, y7 = bfhi(hu.w) + a7 * rz;
    float sum = y0 + y1 + y2 + y3 + y4 + y5 + y6 + y7;
    float sq  = y0*y0 + y1*y1 + y2*y2 + y3*y3 + y4*y4 + y5*y5 + y6*y6 + y7*y7;
    #pragma unroll
    for (int m = 1; m < 16; m <<= 1){        // quarter's 16 lanes hold all 128 dims
        sum += __shfl_xor(sum, m);
        sq  += __shfl_xor(sq,  m);
    }
    float mu  = sum * (1.f / 128.f);
    float var = sq * (1.f / 128.f) - mu * mu;
    var = var < 0.f ? 0.f : var;
    float inv = rsqrtf(var + 1e-5f);
    int c = gq * 8;
    float4 gm0 = *reinterpret_cast<const float4*>(gw + c);
    float4 gm1 = *reinterpret_cast<const float4*>(gw + c + 4);
    float4 bt0 = *reinterpret_cast<const float4*>(bta + c);
    float4 bt1 = *reinterpret_cast<const float4*>(bta + c + 4);
    float o0 = fmaf(gm0.x * (y0 - mu), inv, bt0.x);
    float o1 = fmaf(gm0.y * (y1 - mu), inv, bt0.y);
    float o2 = fmaf(gm0.z * (y2 - mu), inv, bt0.z);
    float o3 = fmaf(gm0.w * (y3 - mu), inv, bt0.w);
    float o4 = fmaf(gm1.x * (y4 - mu), inv, bt1.x);
    float o5 = fmaf(gm1.y * (y5 - mu), inv, bt1.y);
    float o6 = fmaf(gm1.z * (y6 - mu), inv, bt1.z);
    float o7 = fmaf(gm1.w * (y7 - mu), inv, bt1.w);
    o0 = o0 > 0.f ? o0 : 0.f;  o1 = o1 > 0.f ? o1 : 0.f;
    o2 = o2 > 0.f ? o2 : 0.f;  o3 = o3 > 0.f ? o3 : 0.f;
    o4 = o4 > 0.f ? o4 : 0.f;  o5 = o5 > 0.f ? o5 : 0.f;
    o6 = o6 > 0.f ? o6 : 0.f;  o7 = o7 > 0.f ? o7 : 0.f;
    *reinterpret_cast<uint4*>(hb + p) = make_uint4(
        pack2(o0, o1), pack2(o2, o3), pack2(o4, o5), pack2(o6, o7));
}

// ---------------- link prediction: sigmoid(h[src] . h[dst]) (bf16) ----------------
__global__ __launch_bounds__(256) void pair_kernel(const u16* __restrict__ hb,
                                                   const int* __restrict__ src,
                                                   const int* __restrict__ dst,
                                                   float* __restrict__ out){
    int tid = threadIdx.x;
    int pid = blockIdx.x * 16 + (tid >> 4);
    int sub = tid & 15;
    int s = src[pid], d = dst[pid];
    uint4 a = *reinterpret_cast<const uint4*>(hb + (size_t)s * 128 + sub * 8);
    uint4 b = *reinterpret_cast<const uint4*>(hb + (size_t)d * 128 + sub * 8);
    float dot = bflo(a.x) * bflo(b.x) + bfhi(a.x) * bfhi(b.x)
              + bflo(a.y) * bflo(b.y) + bfhi(a.y) * bfhi(b.y)
              + bflo(a.z) * bflo(b.z) + bfhi(a.z) * bfhi(b.z)
              + bflo(a.w) * bflo(b.w) + bfhi(a.w) * bfhi(b.w);
    dot += __shfl_xor(dot, 1); dot += __shfl_xor(dot, 2);
    dot += __shfl_xor(dot, 4); dot += __shfl_xor(dot, 8);
    if (sub == 0) out[pid] = 1.f / (1.f + __expf(-dot));
}

extern "C" void kernel_launch(void* const* d_in, const int* in_sizes, int n_in,
                              void* d_out, int out_size, void* d_ws, size_t ws_size,
                              hipStream_t stream){
    const float* x      = (const float*)d_in[0];
    const float* rw     = (const float*)d_in[1];
    const int*   ei     = (const int*)  d_in[2];
    const int*   src    = (const int*)  d_in[3];
    const int*   dst    = (const int*)  d_in[4];
    const float* W_rwse = (const float*)d_in[5];
    const float* b_rwse = (const float*)d_in[6];
    const float* W_in   = (const float*)d_in[7];
    const float* b_in   = (const float*)d_in[8];
    const float* Wq     = (const float*)d_in[9];
    const float* bq     = (const float*)d_in[10];
    const float* Wk     = (const float*)d_in[11];
    const float* bk     = (const float*)d_in[12];
    const float* Wv     = (const float*)d_in[13];
    const float* bv     = (const float*)d_in[14];
    const float* Wsk    = (const float*)d_in[15];
    const float* bsk    = (const float*)d_in[16];
    const float* ln_g   = (const float*)d_in[17];
    const float* ln_b   = (const float*)d_in[18];
    float* out = (float*)d_out;

    char* p = (char*)d_ws;
    auto carve = [&](size_t bytes) -> char* {
        char* r = p; p += (bytes + 255) & ~(size_t)255; return r;
    };
    u16*   hb    = (u16*) carve((size_t)NN * 128 * 2);   // 25.6 MB
    u8*    qb    = (u8*)  carve((size_t)NN * 128 * 2);   // int8 (or bf16 fallback)
    u8*    kvb   = (u8*)  carve((size_t)NN * 256);       // 25.6 MB int8 k | fp8 v
    u16*   hsb   = (u16*) carve((size_t)NN * 128 * 2);   // h + skip prefused
    int*   offs  = (int*) carve((size_t)NN * 4);
    int*   deg   = (int*) carve((size_t)NN * 4);
    int*   ebuf  = (int*) carve((size_t)EE * 4);         // 4 MB (byte offsets)
    u32*   bkt   = (u32*) carve((size_t)EE * 4);         // 4 MB packed records
    int*   bcnt  = (int*) carve((size_t)BKT * 4);
    int*   bstart= (int*) carve((size_t)BKT * 4);
    int*   bwork = (int*) carve((size_t)BKT * 4);
    int*   perm  = (int*) carve((size_t)NN * 4);
    int*   dh    = (int*) carve((size_t)256 * 4);
    int*   dcur  = (int*) carve((size_t)256 * 4);
    u16*   Wb2   = (u16*) carve((size_t)2 * 128 * 512 * 2);  // 256 KB
    u16*   Winb  = (u16*) carve((size_t)8 * 5 * 512 * 2);    //  40 KB

    hipMemsetAsync(bcnt, 0, (size_t)BKT * 4, stream);
    hipMemsetAsync(dh, 0, (size_t)256 * 4, stream);

    winprep_kernel<<<10, 256, 0, stream>>>(W_in, Winb);
    wprep_kernel<<<64, 256, 0, stream>>>(Wq, Wk, Wv, Wsk, Wb2);
    inproj_mfma<<<(NN + 63) / 64, 512, 0, stream>>>(x, rw, W_rwse, b_rwse,
                                                    Winb, b_in, hb);
    bhist_kernel<<<512, 256, 0, stream>>>(ei + EE, bcnt);
    bscan_kernel<<<1, 256, 0, stream>>>(bcnt, bstart, bwork);
    bpart_kernel<<<512, 256, 0, stream>>>(ei, bwork, bkt);
    bcsr_kernel<<<BKT, 256, 0, stream>>>(bstart, bcnt, bkt, offs, deg, ebuf);
    dhist_kernel<<<256, 256, 0, stream>>>(deg, dh);
    dscan_kernel<<<1, 256, 0, stream>>>(dh, dcur);
    dfill_kernel<<<256, 256, 0, stream>>>(deg, dcur, perm);

    for (int l = 0; l < 2; ++l){
        gemm4_mfma<<<(NN + 63) / 64, 512, 0, stream>>>(hb, Wb2 + (size_t)l * 65536,
            bq + l * 128, bk + l * 128, bv + l * 128, bsk + l * 128,
            qb, kvb, hsb);
        attn_kernel<<<NN / 16, 256, 0, stream>>>(hb, qb, kvb, hsb,
            offs, deg, ebuf, perm, ln_g + l * 128, ln_b + l * 128);
    }
    pair_kernel<<<NPAIRSC / 16, 256, 0, stream>>>(hb, src, dst, out);
}